// Round 1
// 3321.655 us; speedup vs baseline: 1.0450x; 1.0450x over previous
//
#include <hip/hip_runtime.h>
#include <cstdint>
#include <cstddef>

// QLSTM on MI355X. Persistent kernel, 64 WGs (4 batch-groups x 16 hidden-
// slices), 1 block/CU by capacity. Weights resident in VGPRs (bf16
// B-fragments). Cross-block h exchange via FINE-GRAINED device-coherent
// (sc1) relaxed atomics: no buffer_wbl2 / buffer_inv cache-wide ops, no
// RMW flag contention, no LDS staging round-trip.
//
// Protocol per step t:
//   producer: h stores (relaxed agent u32, write-through) -> __syncthreads
//             (drains vmcnt(0) per wave) -> relaxed agent flag store = 1.
//   consumer: x-MFMAs first (overlap peers' publish), then 16 threads each
//             poll one producer flag (relaxed agent load), barrier, then
//             read A-frags straight from hbuf (relaxed agent u64 loads).
// Ping-pong hbuf slots; flag[t+2] full => all peers read slot((t+1)&1),
// so rewriting it at step t+2 is safe (same invariant as before).

#define SEQ 512
#define BATCH 256
#define IN_DIMX 256
#define HIDN 256
#define DTOT 512

typedef float f32x4 __attribute__((ext_vector_type(4)));
typedef short s16x8 __attribute__((ext_vector_type(8)));

__device__ __forceinline__ unsigned short f2bf(float f) {
  unsigned u = __builtin_bit_cast(unsigned, f);
  u += 0x7FFFu + ((u >> 16) & 1u);   // RNE to bf16
  return (unsigned short)(u >> 16);
}

__device__ __forceinline__ float sigm(float x) {
  return __builtin_amdgcn_rcpf(1.0f + __expf(-x));
}
__device__ __forceinline__ float tanh_fast(float x) {
  return 1.0f - 2.0f * __builtin_amdgcn_rcpf(1.0f + __expf(2.0f * x));
}

// hbuf[0] <- h0 (bf16, [bm4][kc32][row64][8] layout), zero the flag array.
// flags layout: [(SEQ+2)][4 bm][16 js] ints (one word per producer block).
__global__ void qlstm_prep(const float* __restrict__ h0,
                           unsigned short* __restrict__ hbuf,
                           int* __restrict__ flags) {
  int tid = blockIdx.x * blockDim.x + threadIdx.x;   // 65536 threads
  if (tid < (SEQ + 2) * 4 * 16) flags[tid] = 0;
  int bm = tid >> 14, kc = (tid >> 9) & 31, row = (tid >> 3) & 63, j = tid & 7;
  hbuf[tid] = f2bf(h0[(bm * 64 + row) * HIDN + kc * 8 + j]);
}

__launch_bounds__(256, 1)
__global__ void qlstm_main(
    const float* __restrict__ X, const float* __restrict__ c0,
    const float* __restrict__ Wf, const float* __restrict__ bf_,
    const float* __restrict__ thf, const float* __restrict__ scf,
    const float* __restrict__ Wi, const float* __restrict__ bi_,
    const float* __restrict__ thi, const float* __restrict__ sci,
    const float* __restrict__ Wu, const float* __restrict__ bu_,
    const float* __restrict__ thu, const float* __restrict__ scu,
    const float* __restrict__ Wo, const float* __restrict__ bo_,
    const float* __restrict__ tho, const float* __restrict__ sco,
    float* __restrict__ out,
    unsigned short* __restrict__ hbuf,
    int* __restrict__ flags) {
  const int tid = threadIdx.x;
  const int wave = tid >> 6;
  const int lane = tid & 63;
  const int quad = lane >> 4;
  const int col = lane & 15;          // MFMA n-index / C col / A m-index
  const int bm = blockIdx.x & 3;      // batch group (64 rows)
  const int js = blockIdx.x >> 2;     // hidden slice (16 cols)

  // ---- resident weight fragments (bf16), loaded once ----
  // B-frag for 16x16x32: B[k = quad*8 + j][n = col]; B[k][n] = W_g[js*16+n][k]
  s16x8 wx[4][8], wh[4][8];   // 256 VGPRs
  {
    const float* Wg[4] = {Wf, Wi, Wu, Wo};
#pragma unroll
    for (int g = 0; g < 4; ++g) {
      const float* wr = Wg[g] + (size_t)(js * 16 + col) * DTOT + quad * 8;
#pragma unroll
      for (int s = 0; s < 16; ++s) {
        float4 p0 = *(const float4*)(wr + s * 32);
        float4 p1 = *(const float4*)(wr + s * 32 + 4);
        s16x8 fr;
        fr[0] = (short)f2bf(p0.x); fr[1] = (short)f2bf(p0.y);
        fr[2] = (short)f2bf(p0.z); fr[3] = (short)f2bf(p0.w);
        fr[4] = (short)f2bf(p1.x); fr[5] = (short)f2bf(p1.y);
        fr[6] = (short)f2bf(p1.z); fr[7] = (short)f2bf(p1.w);
        if (s < 8) wx[g][s] = fr; else wh[g][s - 8] = fr;
      }
    }
  }
  float th[4], sc[4], bi[4];
  {
    const float* Tg[4] = {thf, thi, thu, tho};
    const float* Sg[4] = {scf, sci, scu, sco};
    const float* Bg[4] = {bf_, bi_, bu_, bo_};
#pragma unroll
    for (int g = 0; g < 4; ++g) {
      th[g] = Tg[g][js * 16 + col];
      sc[g] = Sg[g][js * 16 + col];
      bi[g] = Bg[g][js * 16 + col];
    }
  }

  // c state: C/D layout row = quad*4 + r, col = lane&15
  const int browq = bm * 64 + wave * 16 + quad * 4;
  float c[4];
#pragma unroll
  for (int r = 0; r < 4; ++r)
    c[r] = c0[(size_t)(browq + r) * HIDN + js * 16 + col];

  const float* Xrow = X + (size_t)(bm * 64 + wave * 16 + col) * IN_DIMX + quad * 8;
  const int kc_out = js * 2 + (col >> 3);
  const int jsub = col & 7;
  const int rowA = wave * 16 + col;   // A-frag batch row for this lane

#pragma clang loop unroll(disable)
  for (int t = 0; t < SEQ; ++t) {
    // ---- x side: load, convert, MFMA — all BEFORE the flag wait so it
    // overlaps the peers' publish latency ----
    float4 xv[8][2];
    {
      const float* xb = Xrow + (size_t)t * BATCH * IN_DIMX;
#pragma unroll
      for (int s = 0; s < 8; ++s) {
        xv[s][0] = *(const float4*)(xb + s * 32);
        xv[s][1] = *(const float4*)(xb + s * 32 + 4);
      }
    }
    s16x8 xf[8];
#pragma unroll
    for (int s = 0; s < 8; ++s) {
      s16x8 fr;
      fr[0] = (short)f2bf(xv[s][0].x); fr[1] = (short)f2bf(xv[s][0].y);
      fr[2] = (short)f2bf(xv[s][0].z); fr[3] = (short)f2bf(xv[s][0].w);
      fr[4] = (short)f2bf(xv[s][1].x); fr[5] = (short)f2bf(xv[s][1].y);
      fr[6] = (short)f2bf(xv[s][1].z); fr[7] = (short)f2bf(xv[s][1].w);
      xf[s] = fr;
    }

    f32x4 acc[4];
#pragma unroll
    for (int g = 0; g < 4; ++g) acc[g] = (f32x4){bi[g], bi[g], bi[g], bi[g]};

#pragma unroll
    for (int s = 0; s < 8; ++s) {
#pragma unroll
      for (int g = 0; g < 4; ++g)
        acc[g] = __builtin_amdgcn_mfma_f32_16x16x32_bf16(xf[s], wx[g][s], acc[g], 0, 0, 0);
    }

    // ---- wait for h(t): 16 threads poll the 16 producer flags in parallel.
    // Relaxed agent loads (sc1) -> no buffer_inv per poll, L2 keeps X cached.
    if (t > 0) {
      if (tid < 16) {
        int* fp = flags + ((size_t)t * 4 + bm) * 16 + tid;
        while (__hip_atomic_load(fp, __ATOMIC_RELAXED,
                                 __HIP_MEMORY_SCOPE_AGENT) == 0) {
          __builtin_amdgcn_s_sleep(1);
        }
      }
      __syncthreads();   // all waves gated on the pollers; orders h loads after
    }

    // ---- h side: A-frags read DIRECTLY from hbuf (each element is consumed
    // by exactly one lane -> LDS staging was a wasted round trip).
    // Relaxed agent u64 loads read the coherent point (no stale local L2).
    {
      const unsigned short* hsrc = hbuf + ((size_t)((t & 1) * 4 + bm)) * 16384;
      unsigned long long q[16];
#pragma unroll
      for (int s = 0; s < 8; ++s) {
        unsigned long long* p = (unsigned long long*)
            (hsrc + (size_t)((s * 4 + quad) * 64 + rowA) * 8);
        q[2 * s]     = __hip_atomic_load(p,     __ATOMIC_RELAXED, __HIP_MEMORY_SCOPE_AGENT);
        q[2 * s + 1] = __hip_atomic_load(p + 1, __ATOMIC_RELAXED, __HIP_MEMORY_SCOPE_AGENT);
      }
#pragma unroll
      for (int s = 0; s < 8; ++s) {
        union { unsigned long long qq[2]; s16x8 v; } u;
        u.qq[0] = q[2 * s]; u.qq[1] = q[2 * s + 1];
#pragma unroll
        for (int g = 0; g < 4; ++g)
          acc[g] = __builtin_amdgcn_mfma_f32_16x16x32_bf16(u.v, wh[g][s], acc[g], 0, 0, 0);
      }
    }

    // ---- gates + state update; acc tiles 0..3 = f,i,u,o at identical (b,j)
    unsigned int* hdst32 = (unsigned int*)
        (hbuf + ((size_t)(((t + 1) & 1) * 4 + bm)) * 16384);
    float* orow = out + (size_t)t * BATCH * HIDN;
#pragma unroll
    for (int r = 0; r < 4; ++r) {
      float fg = sigm(sigm(__sinf(acc[0][r] * th[0]) * sc[0]));
      float ig = sigm(sigm(__sinf(acc[1][r] * th[1]) * sc[1]));
      float gg = tanh_fast(sigm(__sinf(acc[2][r] * th[2]) * sc[2]));
      float og = sigm(sigm(__sinf(acc[3][r] * th[3]) * sc[3]));
      float cn = fg * c[r] + ig * gg;
      c[r] = cn;
      float hh = og * tanh_fast(cn);
      int brow = browq + r;
      orow[(size_t)brow * HIDN + js * 16 + col] = hh;
      // publish h(t+1) as write-through dwords: lanes (col even, col odd)
      // hold the two bf16 halves of one dword in the [kc][row][8] layout.
      float ph = __shfl_xor(hh, 1);
      if ((col & 1) == 0) {
        unsigned int w = (unsigned)f2bf(hh) | ((unsigned)f2bf(ph) << 16);
        __hip_atomic_store(
            &hdst32[(size_t)(kc_out * 64 + wave * 16 + quad * 4 + r) * 4 + (jsub >> 1)],
            w, __ATOMIC_RELAXED, __HIP_MEMORY_SCOPE_AGENT);
      }
      if (t == SEQ - 1) {
        out[(size_t)SEQ * BATCH * HIDN + (size_t)brow * HIDN + js * 16 + col] = hh;
        out[(size_t)SEQ * BATCH * HIDN + (size_t)BATCH * HIDN +
            (size_t)brow * HIDN + js * 16 + col] = cn;
      }
    }

    // ---- release: barrier drains every wave's vmcnt(0) (write-through h
    // stores are then visible at the coherent point), then one relaxed flag
    // store. No buffer_wbl2, no RMW.
    __syncthreads();
    if (tid == 0) {
      asm volatile("s_waitcnt vmcnt(0)" ::: "memory");   // belt-and-braces
      __hip_atomic_store(flags + ((size_t)(t + 1) * 4 + bm) * 16 + js, 1,
                         __ATOMIC_RELAXED, __HIP_MEMORY_SCOPE_AGENT);
    }
  }
}

extern "C" void kernel_launch(void* const* d_in, const int* in_sizes, int n_in,
                              void* d_out, int out_size, void* d_ws, size_t ws_size,
                              hipStream_t stream) {
  (void)in_sizes; (void)n_in; (void)out_size; (void)ws_size;
  const float* X   = (const float*)d_in[0];
  const float* h0  = (const float*)d_in[1];
  const float* c0  = (const float*)d_in[2];
  const float* Wf  = (const float*)d_in[3];
  const float* bf_ = (const float*)d_in[4];
  const float* thf = (const float*)d_in[5];
  const float* scf = (const float*)d_in[6];
  const float* Wi  = (const float*)d_in[7];
  const float* bi_ = (const float*)d_in[8];
  const float* thi = (const float*)d_in[9];
  const float* sci = (const float*)d_in[10];
  const float* Wu  = (const float*)d_in[11];
  const float* bu_ = (const float*)d_in[12];
  const float* thu = (const float*)d_in[13];
  const float* scu = (const float*)d_in[14];
  const float* Wo  = (const float*)d_in[15];
  const float* bo_ = (const float*)d_in[16];
  const float* tho = (const float*)d_in[17];
  const float* sco = (const float*)d_in[18];
  float* out = (float*)d_out;

  unsigned short* hbuf = (unsigned short*)d_ws;            // 2*4*16384 u16 = 256 KB
  int* flags = (int*)((char*)d_ws + 262144);               // (SEQ+2)*4*16 ints = 128.5 KB

  hipLaunchKernelGGL(qlstm_prep, dim3(256), dim3(256), 0, stream, h0, hbuf, flags);

  // Plain launch: 64 blocks, 1 block/CU -> all resident on a 256-CU device.
  hipLaunchKernelGGL(qlstm_main, dim3(64), dim3(256), 0, stream,
                     X, c0, Wf, bf_, thf, scf, Wi, bi_, thi, sci,
                     Wu, bu_, thu, scu, Wo, bo_, tho, sco,
                     out, hbuf, flags);
}